// Round 6
// baseline (98.570 us; speedup 1.0000x reference)
//
#include <hip/hip_runtime.h>
#include <math.h>

#define N_TOK 8192
#define DIM   1024
#define NE    8
#define NR    16
#define NO    3072
#define OUT_ELEMS (N_TOK * NO)   // 25165824
#define NBLK_A 1024
#define NBLK_D 1031

__device__ __forceinline__ float softplusf(float z) {
  return z > 0.f ? z + log1pf(expf(-z)) : log1pf(expf(z));
}
__device__ __forceinline__ float ncdf(float z) {
  return 0.5f * erfcf(-z * 0.70710678118654752f);
}

#define FMA4(A, S, W) { (A).x = fmaf((S),(W).x,(A).x); (A).y = fmaf((S),(W).y,(A).y); \
                        (A).z = fmaf((S),(W).z,(A).z); (A).w = fmaf((S),(W).w,(A).w); }
#define Z4 make_float4(0.f,0.f,0.f,0.f)

// quad cross-lane add via DPP (VALU pipe): xor1=quad_perm[1,0,3,2]=0xB1, xor2=[2,3,0,1]=0x4E
#define DPP_ADD(V, CTRL) ((V) + __int_as_float(__builtin_amdgcn_update_dpp(0, __float_as_int(V), (CTRL), 0xf, 0xf, true)))
#define QRED4(A) { (A).x = DPP_ADD((A).x, 0xB1); (A).y = DPP_ADD((A).y, 0xB1); \
                   (A).z = DPP_ADD((A).z, 0xB1); (A).w = DPP_ADD((A).w, 0xB1); \
                   (A).x = DPP_ADD((A).x, 0x4E); (A).y = DPP_ADD((A).y, 0x4E); \
                   (A).z = DPP_ADD((A).z, 0x4E); (A).w = DPP_ADD((A).w, 0x4E); }

// ---------------------------------------------------------------------------
// Kernel A: gating GEMV + fused final reduction (last block).
// 8 tokens/block x 1024 blocks. Thread t owns d=[4t,4t+4); 16 gate/noise
// weights register-resident; all 8 token float4 loads issued upfront;
// DPP quad-reduce -> LDS dump -> 2-round wave stage-2 -> epilogue (t<8).
// Last block (atomic counter) reduces 1024x16 partials -> importance/load/
// counts/fill (replaces kernel kB).
// ---------------------------------------------------------------------------
__global__ __launch_bounds__(256, 3) void kA(const float* __restrict__ x,
    const float* __restrict__ wg, const float* __restrict__ wn,
    const float* __restrict__ nz, int* __restrict__ eid, float* __restrict__ part,
    float* __restrict__ outIL, int* __restrict__ counts, int* __restrict__ fill,
    unsigned int* __restrict__ done) {
  __shared__ float pd[8][64][20];   // [token][quad][16 outs + pad]
  __shared__ float lgS[8][20];
  __shared__ float red[16][16];
  __shared__ int lastFlag;
  int t = threadIdx.x;
  int n0 = blockIdx.x << 3;
  int qd = t >> 2, l2 = t & 3, wid = t >> 6, lane = t & 63;
  const float* wgp = wg + (size_t)(t << 2) * NE;
  const float* wnp = wn + (size_t)(t << 2) * NE;
  float4 g0a = *(const float4*)(wgp + 0),  g0b = *(const float4*)(wgp + 4);
  float4 g1a = *(const float4*)(wgp + 8),  g1b = *(const float4*)(wgp + 12);
  float4 g2a = *(const float4*)(wgp + 16), g2b = *(const float4*)(wgp + 20);
  float4 g3a = *(const float4*)(wgp + 24), g3b = *(const float4*)(wgp + 28);
  float4 q0a = *(const float4*)(wnp + 0),  q0b = *(const float4*)(wnp + 4);
  float4 q1a = *(const float4*)(wnp + 8),  q1b = *(const float4*)(wnp + 12);
  float4 q2a = *(const float4*)(wnp + 16), q2b = *(const float4*)(wnp + 20);
  float4 q3a = *(const float4*)(wnp + 24), q3b = *(const float4*)(wnp + 28);
  const float* xb = x + (size_t)n0 * DIM + (t << 2);
  float4 xc0 = *(const float4*)(xb + 0 * DIM);
  float4 xc1 = *(const float4*)(xb + 1 * DIM);
  float4 xc2 = *(const float4*)(xb + 2 * DIM);
  float4 xc3 = *(const float4*)(xb + 3 * DIM);
  float4 xc4 = *(const float4*)(xb + 4 * DIM);
  float4 xc5 = *(const float4*)(xb + 5 * DIM);
  float4 xc6 = *(const float4*)(xb + 6 * DIM);
  float4 xc7 = *(const float4*)(xb + 7 * DIM);
  #define TOKEN(K, XC) { \
    float4 aA = Z4, aB = Z4, aC = Z4, aD = Z4; \
    FMA4(aA, (XC).x, g0a); FMA4(aB, (XC).x, g0b); FMA4(aC, (XC).x, q0a); FMA4(aD, (XC).x, q0b); \
    FMA4(aA, (XC).y, g1a); FMA4(aB, (XC).y, g1b); FMA4(aC, (XC).y, q1a); FMA4(aD, (XC).y, q1b); \
    FMA4(aA, (XC).z, g2a); FMA4(aB, (XC).z, g2b); FMA4(aC, (XC).z, q2a); FMA4(aD, (XC).z, q2b); \
    FMA4(aA, (XC).w, g3a); FMA4(aB, (XC).w, g3b); FMA4(aC, (XC).w, q3a); FMA4(aD, (XC).w, q3b); \
    QRED4(aA); QRED4(aB); QRED4(aC); QRED4(aD); \
    if (l2 == 0) { \
      *(float4*)&pd[K][qd][0]  = aA; *(float4*)&pd[K][qd][4]  = aB; \
      *(float4*)&pd[K][qd][8]  = aC; *(float4*)&pd[K][qd][12] = aD; } }
  TOKEN(0, xc0) TOKEN(1, xc1) TOKEN(2, xc2) TOKEN(3, xc3)
  TOKEN(4, xc4) TOKEN(5, xc5) TOKEN(6, xc6) TOKEN(7, xc7)
  #undef TOKEN
  __syncthreads();
  #pragma unroll
  for (int rnd = 0; rnd < 2; ++rnd) {
    int tok = (rnd << 2) + wid;
    int o = lane >> 2, r2 = lane & 3;
    float s = 0.f;
    #pragma unroll
    for (int j = 0; j < 16; ++j) s += pd[tok][(j << 2) + r2][o];
    s = DPP_ADD(s, 0xB1); s = DPP_ADD(s, 0x4E);
    if (r2 == 0) lgS[tok][o] = s;
  }
  __syncthreads();
  if (t < 8) {
    int n = n0 + t;
    float cl[8], st[8], lg[8];
    float4 nzv0 = *(const float4*)(nz + (size_t)n * NE);
    float4 nzv1 = *(const float4*)(nz + (size_t)n * NE + 4);
    float nzv[8] = {nzv0.x, nzv0.y, nzv0.z, nzv0.w, nzv1.x, nzv1.y, nzv1.z, nzv1.w};
    #pragma unroll
    for (int e = 0; e < 8; ++e) cl[e] = lgS[t][e];
    #pragma unroll
    for (int e = 0; e < 8; ++e) {
      st[e] = softplusf(lgS[t][8 + e]) + 0.01f;
      lg[e] = fmaf(nzv[e], st[e], cl[e]);
    }
    float m1 = -1e30f, m2 = -1e30f; int idx = 0;
    #pragma unroll
    for (int e = 0; e < 8; ++e) {
      float v = lg[e];
      if (v > m1)      { m2 = m1; m1 = v; idx = e; }
      else if (v > m2) { m2 = v; }
    }
    eid[n] = idx;
    float pr[8], cw[8];
    #pragma unroll
    for (int e = 0; e < 8; ++e) {
      float thr = (lg[e] > m2) ? m2 : m1;
      pr[e] = ncdf((cl[e] - thr) / st[e]);
    }
    #pragma unroll
    for (int e = 0; e < 8; ++e) cw[e] = (float)__popcll(__ballot(idx == e));
    #pragma unroll
    for (int e = 0; e < 8; ++e) {
      #pragma unroll
      for (int off = 1; off <= 4; off <<= 1) pr[e] += __shfl_xor(pr[e], off);
    }
    if (t == 0) {
      #pragma unroll
      for (int e = 0; e < 8; ++e) {
        part[blockIdx.x * 16 + e]     = cw[e];
        part[blockIdx.x * 16 + 8 + e] = pr[e];
      }
    }
  }
  __syncthreads();
  if (t == 0) {
    __threadfence();
    unsigned int old = atomicAdd(done, 1u);
    lastFlag = (old == NBLK_A - 1) ? 1 : 0;
  }
  __syncthreads();
  if (lastFlag) {   // fused kB: reduce 1024x16 partials
    __threadfence();
    int s = t & 15, g = t >> 4;
    float sum = 0.f;
    for (int j = 0; j < 64; ++j) sum += part[(g + 16 * j) * 16 + s];
    red[g][s] = sum;
    __syncthreads();
    if (t < 16) {
      float tot = 0.f;
      #pragma unroll
      for (int gg = 0; gg < 16; ++gg) tot += red[gg][t];
      outIL[t] = tot;
      if (t < 8) { counts[t] = (int)(tot + 0.5f); fill[t] = 0; }
    }
  }
}

// ---------------------------------------------------------------------------
// Kernel C: bucket tokens by expert (LDS hist + 8 global atomics per block).
// ---------------------------------------------------------------------------
__global__ __launch_bounds__(256) void kC(const int* __restrict__ eid,
    const int* __restrict__ counts, int* __restrict__ fill, int* __restrict__ bucket) {
  __shared__ int lcnt[8], lbase[8];
  int t = threadIdx.x;
  if (t < 8) lcnt[t] = 0;
  __syncthreads();
  int n = blockIdx.x * 256 + t;
  int e = eid[n];
  int rank = atomicAdd(&lcnt[e], 1);
  __syncthreads();
  if (t < 8) lbase[t] = atomicAdd(&fill[t], lcnt[t]);
  __syncthreads();
  int off = 0;
  #pragma unroll
  for (int i = 0; i < 8; ++i) if (i < e) off += counts[i];
  bucket[off + lbase[e] + rank] = n;
}

// ---------------------------------------------------------------------------
// Kernel D: h_sorted[p] = lora_a[e] @ x[bucket[p]], 8 tokens/tile.
// Same high-concurrency structure as kA: la[e] rows register-resident,
// 8 gathered token loads upfront, DPP quad-reduce + LDS stage-2.
// ---------------------------------------------------------------------------
__global__ __launch_bounds__(256, 3) void kD(const float* __restrict__ x,
    const float* __restrict__ la, const int* __restrict__ counts,
    const int* __restrict__ bucket, float* __restrict__ h) {
  __shared__ float pd[8][64][20];
  __shared__ float hS[8][20];
  __shared__ int toks[8];
  int tile = blockIdx.x;
  int e = -1, jt = 0, off = 0;
  { int tot = 0, o = 0;
    #pragma unroll
    for (int i = 0; i < 8; ++i) {
      int c = counts[i]; int nt = (c + 7) >> 3;
      if (e < 0 && tile < tot + nt) { e = i; jt = tile - tot; off = o; }
      tot += nt; o += c;
    } }
  if (e < 0) return;
  int cnt = counts[e];
  int p0 = off + (jt << 3);
  int valid = min(8, cnt - (jt << 3));
  int t = threadIdx.x;
  if (t < 8) toks[t] = bucket[p0 + min(t, valid - 1)];
  int qd = t >> 2, l2 = t & 3, wid = t >> 6, lane = t & 63;
  const float* ap = la + (size_t)e * NR * DIM + (t << 2);
  float4 w0  = *(const float4*)(ap + 0  * DIM), w1  = *(const float4*)(ap + 1  * DIM);
  float4 w2  = *(const float4*)(ap + 2  * DIM), w3  = *(const float4*)(ap + 3  * DIM);
  float4 w4  = *(const float4*)(ap + 4  * DIM), w5  = *(const float4*)(ap + 5  * DIM);
  float4 w6  = *(const float4*)(ap + 6  * DIM), w7  = *(const float4*)(ap + 7  * DIM);
  float4 w8  = *(const float4*)(ap + 8  * DIM), w9  = *(const float4*)(ap + 9  * DIM);
  float4 w10 = *(const float4*)(ap + 10 * DIM), w11 = *(const float4*)(ap + 11 * DIM);
  float4 w12 = *(const float4*)(ap + 12 * DIM), w13 = *(const float4*)(ap + 13 * DIM);
  float4 w14 = *(const float4*)(ap + 14 * DIM), w15 = *(const float4*)(ap + 15 * DIM);
  __syncthreads();
  int dof = t << 2;
  float4 xc0 = *(const float4*)(x + (size_t)toks[0] * DIM + dof);
  float4 xc1 = *(const float4*)(x + (size_t)toks[1] * DIM + dof);
  float4 xc2 = *(const float4*)(x + (size_t)toks[2] * DIM + dof);
  float4 xc3 = *(const float4*)(x + (size_t)toks[3] * DIM + dof);
  float4 xc4 = *(const float4*)(x + (size_t)toks[4] * DIM + dof);
  float4 xc5 = *(const float4*)(x + (size_t)toks[5] * DIM + dof);
  float4 xc6 = *(const float4*)(x + (size_t)toks[6] * DIM + dof);
  float4 xc7 = *(const float4*)(x + (size_t)toks[7] * DIM + dof);
  #define DOTC(ACC, W, XC) ACC = fmaf((XC).x,(W).x, fmaf((XC).y,(W).y, fmaf((XC).z,(W).z, fmaf((XC).w,(W).w,(ACC)))))
  #define TOKEN(K, XC) { \
    float4 aA = Z4, aB = Z4, aC = Z4, aD = Z4; \
    DOTC(aA.x, w0, XC);  DOTC(aA.y, w1, XC);  DOTC(aA.z, w2, XC);  DOTC(aA.w, w3, XC); \
    DOTC(aB.x, w4, XC);  DOTC(aB.y, w5, XC);  DOTC(aB.z, w6, XC);  DOTC(aB.w, w7, XC); \
    DOTC(aC.x, w8, XC);  DOTC(aC.y, w9, XC);  DOTC(aC.z, w10, XC); DOTC(aC.w, w11, XC); \
    DOTC(aD.x, w12, XC); DOTC(aD.y, w13, XC); DOTC(aD.z, w14, XC); DOTC(aD.w, w15, XC); \
    QRED4(aA); QRED4(aB); QRED4(aC); QRED4(aD); \
    if (l2 == 0) { \
      *(float4*)&pd[K][qd][0]  = aA; *(float4*)&pd[K][qd][4]  = aB; \
      *(float4*)&pd[K][qd][8]  = aC; *(float4*)&pd[K][qd][12] = aD; } }
  TOKEN(0, xc0) TOKEN(1, xc1) TOKEN(2, xc2) TOKEN(3, xc3)
  TOKEN(4, xc4) TOKEN(5, xc5) TOKEN(6, xc6) TOKEN(7, xc7)
  #undef TOKEN
  #undef DOTC
  __syncthreads();
  #pragma unroll
  for (int rnd = 0; rnd < 2; ++rnd) {
    int tok = (rnd << 2) + wid;
    int o = lane >> 2, r2 = lane & 3;
    float s = 0.f;
    #pragma unroll
    for (int j = 0; j < 16; ++j) s += pd[tok][(j << 2) + r2][o];
    s = DPP_ADD(s, 0xB1); s = DPP_ADD(s, 0x4E);
    if (r2 == 0) hS[tok][o] = s;
  }
  __syncthreads();
  if (t < 32) {
    int tok = t >> 2, rq = (t & 3) << 2;
    if (tok < valid) {
      float4 v = make_float4(hS[tok][rq + 0], hS[tok][rq + 1], hS[tok][rq + 2], hS[tok][rq + 3]);
      *(float4*)(h + (size_t)(p0 + tok) * NR + rq) = v;
    }
  }
}

// ---------------------------------------------------------------------------
// Kernel E: out[n] = lora_b[e] @ h. Tiles: 64 tokens x 256 outs.
// ---------------------------------------------------------------------------
__global__ __launch_bounds__(256) void kE(const float* __restrict__ h,
    const float* __restrict__ lb, const int* __restrict__ counts,
    const int* __restrict__ bucket, float* __restrict__ out) {
  __shared__ float bt[16][260];
  __shared__ float ht[16][64];
  __shared__ int toks[64];
  int tile = blockIdx.y;
  int e = -1, jt = 0, off = 0;
  { int tot = 0, o = 0;
    #pragma unroll
    for (int i = 0; i < 8; ++i) {
      int c = counts[i]; int nt = (c + 63) >> 6;
      if (e < 0 && tile < tot + nt) { e = i; jt = tile - tot; off = o; }
      tot += nt; o += c;
    } }
  if (e < 0) return;
  int cnt = counts[e];
  int p0 = off + (jt << 6);
  int valid = min(64, cnt - (jt << 6));
  int o0 = blockIdx.x << 8;
  int t = threadIdx.x;
  if (t < 64) toks[t] = bucket[p0 + min(t, valid - 1)];
  const float* bbase = lb + ((size_t)e * NO + o0) * NR;
  #pragma unroll
  for (int kk = 0; kk < 4; ++kk) {
    int idx = (kk << 8) + t;
    int o = idx >> 2, rq = (idx & 3) << 2;
    float4 v = *(const float4*)(bbase + o * NR + rq);
    bt[rq + 0][o] = v.x; bt[rq + 1][o] = v.y; bt[rq + 2][o] = v.z; bt[rq + 3][o] = v.w;
  }
  { int tok = t >> 2, rq = (t & 3) << 2;
    float4 v = *(const float4*)(h + (size_t)(p0 + min(tok, valid - 1)) * NR + rq);
    ht[rq + 0][tok] = v.x; ht[rq + 1][tok] = v.y; ht[rq + 2][tok] = v.z; ht[rq + 3][tok] = v.w; }
  __syncthreads();
  int og = t & 31, tokg = t >> 5;
  int ob = og << 2, tb = tokg << 3;
  float4 z = Z4;
  float4 aL0=z,aL1=z,aL2=z,aL3=z,aL4=z,aL5=z,aL6=z,aL7=z;
  float4 aH0=z,aH1=z,aH2=z,aH3=z,aH4=z,aH5=z,aH6=z,aH7=z;
  #pragma unroll
  for (int r = 0; r < 16; ++r) {
    float4 blo = *(const float4*)&bt[r][ob];
    float4 bhi = *(const float4*)&bt[r][ob + 128];
    float4 h0  = *(const float4*)&ht[r][tb];
    float4 h1  = *(const float4*)&ht[r][tb + 4];
    FMA4(aL0, h0.x, blo); FMA4(aH0, h0.x, bhi);
    FMA4(aL1, h0.y, blo); FMA4(aH1, h0.y, bhi);
    FMA4(aL2, h0.z, blo); FMA4(aH2, h0.z, bhi);
    FMA4(aL3, h0.w, blo); FMA4(aH3, h0.w, bhi);
    FMA4(aL4, h1.x, blo); FMA4(aH4, h1.x, bhi);
    FMA4(aL5, h1.y, blo); FMA4(aH5, h1.y, bhi);
    FMA4(aL6, h1.z, blo); FMA4(aH6, h1.z, bhi);
    FMA4(aL7, h1.w, blo); FMA4(aH7, h1.w, bhi);
  }
  #define ST(J, AL, AH) { int tt = tb + (J); if (tt < valid) { \
      float* p = out + (size_t)toks[tt] * NO + o0 + ob; \
      *(float4*)p = AL; *(float4*)(p + 128) = AH; } }
  ST(0, aL0, aH0); ST(1, aL1, aH1); ST(2, aL2, aH2); ST(3, aL3, aH3);
  ST(4, aL4, aH4); ST(5, aL5, aH5); ST(6, aL6, aH6); ST(7, aL7, aH7);
  #undef ST
}

// ---------------------------------------------------------------------------
extern "C" void kernel_launch(void* const* d_in, const int* in_sizes, int n_in,
                              void* d_out, int out_size, void* d_ws, size_t ws_size,
                              hipStream_t stream) {
  const float* x  = (const float*)d_in[0];
  const float* wg = (const float*)d_in[1];
  const float* wn = (const float*)d_in[2];
  const float* la = (const float*)d_in[3];
  const float* lb = (const float*)d_in[4];
  const float* nz = (const float*)d_in[5];
  float* out = (float*)d_out;

  char* ws = (char*)d_ws;
  float*        h        = (float*)(ws);                 // 524288 B
  int*          eid      = (int*)  (ws + 524288);        // 32768 B
  int*          bucket   = (int*)  (ws + 557056);        // 32768 B
  float*        partials = (float*)(ws + 589824);        // 65536 B (1024*16*4)
  int*          counts   = (int*)  (ws + 655360);        // 32 B
  int*          fill     = (int*)  (ws + 655392);        // 32 B
  unsigned int* done     = (unsigned int*)(ws + 655424); // 4 B

  hipMemsetAsync(done, 0, 4, stream);
  kA<<<NBLK_A, 256, 0, stream>>>(x, wg, wn, nz, eid, partials,
                                 out + OUT_ELEMS, counts, fill, done);
  kC<<<32, 256, 0, stream>>>(eid, counts, fill, bucket);
  kD<<<NBLK_D, 256, 0, stream>>>(x, la, counts, bucket, h);
  kE<<<dim3(12, 135), 256, 0, stream>>>(h, lb, counts, bucket, out);
}